// Round 5
// baseline (1023.210 us; speedup 1.0000x reference)
//
#include <hip/hip_runtime.h>
#include <cstdio>

using u16 = unsigned short;
using u32 = unsigned int;
using u8  = unsigned char;

typedef __attribute__((ext_vector_type(8))) u16    u16x8;
typedef __attribute__((ext_vector_type(8))) __bf16 bf16x8;
typedef __attribute__((ext_vector_type(4))) float  f32x4;

constexpr int NN = 50000;   // nodes
constexpr int NE = 250000;  // edges
constexpr int EM_REP = 32;  // em replica count
constexpr int NB_SCAN = (NN + 255) / 256;  // 196

// ---------------- ws layout (bytes) ----------------
constexpr size_t OFF_NFA  = 0;                                   // bf16 [NN,256] nfab (nfa cols 0-127, nfb cols 128-255)
constexpr size_t OFF_NFB  = OFF_NFA  + (size_t)NN*128*2;         // (second half of nfab)
constexpr size_t OFF_NFN1 = OFF_NFB  + (size_t)NN*128*2;         // bf16 [NN,128] nf_dense @ Wn1
constexpr size_t OFF_FG   = OFF_NFN1 + (size_t)NN*128*2;         // bf16 [2E,128] f rows then g rows (f-half doubles as ec staging)
constexpr size_t OFF_LIST = OFF_FG   + (size_t)2*NE*128*2;       // u32 [2E] CSR lists
// ---- zeroed region ----
constexpr size_t OFF_NCNT = OFF_LIST + (size_t)2*NE*4;           // u32 [NN] pad 200704
constexpr size_t OFF_ECNT = OFF_NCNT + 200704;                   // u32 [16] pad 256
constexpr size_t OFF_EM32 = OFF_ECNT + 256;                      // f32 [EM_REP,2048]
constexpr size_t OFF_NMA  = OFF_EM32 + (size_t)EM_REP*2048*4;    // f32 [2048]
constexpr size_t OFF_NMC  = OFF_NMA  + 8192;                     // u32 [16] pad 256
constexpr size_t ZERO_SZ  = (OFF_NMC + 256) - OFF_NCNT;
// ---- end zeroed ----
constexpr size_t OFF_OFFA = OFF_NMC  + 256;                      // u32 [NN] CSR offsets (kept)
constexpr size_t OFF_CURS = OFF_OFFA + 200704;                   // u32 [NN] cursors (consumed)
constexpr size_t OFF_BSUM = OFF_CURS + 200704;                   // u32 [196] pad 1024
constexpr size_t OFF_GFP  = OFF_BSUM + 1024;                     // f32 [16,128] gf_pre
constexpr size_t OFF_GFD  = OFF_GFP  + 8192;                     // f32 gf_pre@Wd+emb
constexpr size_t OFF_GFN3 = OFF_GFD  + 8192;                     // f32 gf_pre@Wn3+nmb
constexpr size_t OFF_PACK = OFF_GFN3 + 8192;                     // bf16 packed weights 212992
constexpr size_t OFF_GBK  = OFF_PACK + (size_t)212992*2;         // u8 [2E] per-row graph key (f rows: batch[src], g rows: batch[dst])
constexpr size_t WS_NEED  = OFF_GBK + (size_t)2*NE;

// ---------------- helpers ----------------
static __device__ __forceinline__ float b2f(u16 u) {
    union { u32 u; float f; } x; x.u = ((u32)u) << 16; return x.f;
}
static __device__ __forceinline__ u16 f2bf(float f) {
    union { float f; u32 u; } x; x.f = f;
    u32 r = x.u + 0x7fffu + ((x.u >> 16) & 1u);
    return (u16)(r >> 16);
}
static __device__ __forceinline__ float sp2(float x) {
    return fmaxf(x, 0.f) + __logf(1.f + __expf(-fabsf(x))) - 0.6931471805599453f;
}
static __device__ __forceinline__ bf16x8 ldbf8(const u16* p) {
    return __builtin_bit_cast(bf16x8, *(const u16x8*)p);
}

// ---------------- weight pre-swizzle (fp32 -> bf16 B-fragment order) ----------------
__global__ __launch_bounds__(256) void pack_kernel(
    const float* __restrict__ eW1, const float* __restrict__ eW2,
    const float* __restrict__ nW1, const float* __restrict__ nW2,
    const float* __restrict__ emW, const float* __restrict__ nmW,
    u16* __restrict__ dst)
{
    int gid = blockIdx.x * 256 + threadIdx.x;
    if (gid >= 212992) return;
    const float* src; int rowOff, Nsrc, KC, local;
    if      (gid <  32768) { src=eW1; rowOff=0;   Nsrc=256; KC=4; local=gid; }
    else if (gid <  65536) { src=eW2; rowOff=0;   Nsrc=128; KC=8; local=gid-32768; }
    else if (gid <  98304) { src=nW1; rowOff=0;   Nsrc=256; KC=4; local=gid-65536; }
    else if (gid < 131072) { src=nW2; rowOff=0;   Nsrc=128; KC=8; local=gid-98304; }
    else if (gid < 147456) { src=emW; rowOff=0;   Nsrc=128; KC=4; local=gid-131072; } // Wa
    else if (gid < 163840) { src=emW; rowOff=128; Nsrc=128; KC=4; local=gid-147456; } // Wb
    else if (gid < 180224) { src=emW; rowOff=256; Nsrc=128; KC=4; local=gid-163840; } // Wc
    else if (gid < 196608) { src=nmW; rowOff=0;   Nsrc=128; KC=4; local=gid-180224; } // Wn1
    else                   { src=nmW; rowOff=128; Nsrc=128; KC=4; local=gid-196608; } // Wn2
    int j    = local & 7;
    int lane = (local >> 3) & 63;
    int t    = local >> 9;
    int kc   = t & (KC - 1);
    int nt   = t >> (KC == 8 ? 3 : 2);
    int k = kc * 32 + ((lane >> 4) << 3) + j;
    int n = nt * 16 + (lane & 15);
    dst[gid] = f2bf(src[(size_t)(rowOff + k) * Nsrc + n]);
}

// ---------------- degree / per-graph directed-edge count / per-row graph key ----------------
__global__ __launch_bounds__(256) void deg_kernel(
    const int* __restrict__ ei, const int* __restrict__ batch,
    u32* __restrict__ node_cnt, u32* __restrict__ ecnt, u8* __restrict__ gbk)
{
    __shared__ u32 s_h[16];
    if (threadIdx.x < 16) s_h[threadIdx.x] = 0;
    __syncthreads();
    for (int e = blockIdx.x * 256 + threadIdx.x; e < NE; e += gridDim.x * 256) {
        int s = ei[e], d = ei[NE + e];
        int bs = batch[s], bd = batch[d];
        atomicAdd(&node_cnt[d], 1u);
        atomicAdd(&node_cnt[s], 1u);
        atomicAdd(&s_h[bs], 1u);
        atomicAdd(&s_h[bd], 1u);
        gbk[e]      = (u8)bs;   // f row e keyed by batch[src]
        gbk[NE + e] = (u8)bd;   // g row e keyed by batch[dst]
    }
    __syncthreads();
    if (threadIdx.x < 16 && s_h[threadIdx.x]) atomicAdd(&ecnt[threadIdx.x], s_h[threadIdx.x]);
}

// ---------------- CSR scan (3 passes) + fill ----------------
__global__ __launch_bounds__(256) void scan1_kernel(const u32* __restrict__ ncnt, u32* __restrict__ bsum) {
    __shared__ u32 red[256];
    int i = blockIdx.x * 256 + threadIdx.x;
    red[threadIdx.x] = (i < NN) ? ncnt[i] : 0;
    __syncthreads();
    for (int s = 128; s > 0; s >>= 1) {
        if (threadIdx.x < s) red[threadIdx.x] += red[threadIdx.x + s];
        __syncthreads();
    }
    if (threadIdx.x == 0) bsum[blockIdx.x] = red[0];
}
// parallel exclusive scan over NB_SCAN block sums (one 256-thread block)
__global__ __launch_bounds__(256) void scan2_kernel(u32* __restrict__ bsum) {
    __shared__ u32 sc[256];
    int tid = threadIdx.x;
    u32 v = (tid < NB_SCAN) ? bsum[tid] : 0;
    sc[tid] = v;
    __syncthreads();
    for (int d = 1; d < 256; d <<= 1) {
        u32 t = (tid >= d) ? sc[tid - d] : 0;
        __syncthreads();
        sc[tid] += t;
        __syncthreads();
    }
    if (tid < NB_SCAN) bsum[tid] = sc[tid] - v;
}
__global__ __launch_bounds__(256) void scan3_kernel(
    const u32* __restrict__ ncnt, const u32* __restrict__ boff,
    u32* __restrict__ off, u32* __restrict__ cursor)
{
    __shared__ u32 sc[256];
    int i = blockIdx.x * 256 + threadIdx.x;
    u32 v = (i < NN) ? ncnt[i] : 0;
    sc[threadIdx.x] = v;
    __syncthreads();
    for (int d = 1; d < 256; d <<= 1) {
        u32 t = (threadIdx.x >= d) ? sc[threadIdx.x - d] : 0;
        __syncthreads();
        sc[threadIdx.x] += t;
        __syncthreads();
    }
    u32 excl = sc[threadIdx.x] - v + boff[blockIdx.x];
    if (i < NN) { off[i] = excl; cursor[i] = excl; }
}
__global__ __launch_bounds__(256) void fill_kernel(
    const int* __restrict__ ei, u32* __restrict__ cursor, u32* __restrict__ list)
{
    for (int e = blockIdx.x * 256 + threadIdx.x; e < NE; e += gridDim.x * 256) {
        int s = ei[e], d = ei[NE + e];
        u32 p1 = atomicAdd(&cursor[d], 1u); list[p1] = (u32)e;        // f row -> node d
        u32 p2 = atomicAdd(&cursor[s], 1u); list[p2] = (u32)(NE + e); // g row -> node s
    }
}

// ---------------- node MLP (full-width, nt-split stage1) + 3 projections ----------------
// O0 = nfab (cols 0-127, row stride 256), O1 = nfab+128 (cols 128-255), O2 = nfn1 (stride 128)
__global__ __launch_bounds__(256, 3) void mlp_node_kernel(
    const float* __restrict__ in,
    const u16* __restrict__ W1p, const float* __restrict__ b1,
    const u16* __restrict__ W2p, const float* __restrict__ b2,
    const u16* __restrict__ P0, const u16* __restrict__ P1, const u16* __restrict__ P2,
    u16* __restrict__ O0, u16* __restrict__ O1, u16* __restrict__ O2)
{
    __shared__ __align__(16) u16 sA[64 * 136];   // input tile -> h2
    __shared__ __align__(16) u16 sH[64 * 264];   // h1 tile
    int tid  = threadIdx.x;
    int base = blockIdx.x * 64;
    {
        int r = tid >> 2, p = tid & 3;
        int row = base + r;
        u16* d = sA + r * 136 + p * 32;
        if (row < NN) {
            const float* s = in + (size_t)row * 128 + p * 32;
            #pragma unroll
            for (int i = 0; i < 4; i++) {
                f32x4 f0 = *(const f32x4*)(s + i * 8);
                f32x4 f1 = *(const f32x4*)(s + i * 8 + 4);
                u16x8 v;
                v[0]=f2bf(f0[0]); v[1]=f2bf(f0[1]); v[2]=f2bf(f0[2]); v[3]=f2bf(f0[3]);
                v[4]=f2bf(f1[0]); v[5]=f2bf(f1[1]); v[6]=f2bf(f1[2]); v[7]=f2bf(f1[3]);
                *(u16x8*)(d + i * 8) = v;
            }
        } else {
            u16x8 z = {0,0,0,0,0,0,0,0};
            #pragma unroll
            for (int i = 0; i < 4; i++) *(u16x8*)(d + i * 8) = z;
        }
    }
    __syncthreads();
    int lane = tid & 63, w = tid >> 6, q = lane >> 4, lm = lane & 15;
    // stage 1: nt-split across waves
    {
        bf16x8 a[4][4];
        #pragma unroll
        for (int rt = 0; rt < 4; rt++)
            #pragma unroll
            for (int kc = 0; kc < 4; kc++)
                a[rt][kc] = ldbf8(sA + (rt * 16 + lm) * 136 + kc * 32 + q * 8);
        for (int nti = 0; nti < 4; nti++) {
            int nt = w * 4 + nti;
            bf16x8 bfr[4];
            #pragma unroll
            for (int kc = 0; kc < 4; kc++) bfr[kc] = ldbf8(W1p + nt * 2048 + kc * 512 + lane * 8);
            f32x4 acc[4] = {{0,0,0,0},{0,0,0,0},{0,0,0,0},{0,0,0,0}};
            #pragma unroll
            for (int kc = 0; kc < 4; kc++)
                #pragma unroll
                for (int rt = 0; rt < 4; rt++)
                    acc[rt] = __builtin_amdgcn_mfma_f32_16x16x32_bf16(a[rt][kc], bfr[kc], acc[rt], 0, 0, 0);
            int col = nt * 16 + lm;
            float bias = b1[col];
            #pragma unroll
            for (int rt = 0; rt < 4; rt++)
                #pragma unroll
                for (int r = 0; r < 4; r++)
                    sH[(rt * 16 + q * 4 + r) * 264 + col] = f2bf(sp2(acc[rt][r] + bias));
        }
    }
    __syncthreads();
    // stage 2: row-split
    {
        bf16x8 a[8];
        const u16* ar = sH + (w * 16 + lm) * 264;
        #pragma unroll
        for (int kc = 0; kc < 8; kc++) a[kc] = ldbf8(ar + kc * 32 + q * 8);
        for (int nt = 0; nt < 8; nt++) {
            f32x4 acc = {0.f, 0.f, 0.f, 0.f};
            const u16* bp = W2p + nt * 4096 + lane * 8;
            #pragma unroll
            for (int kc = 0; kc < 8; kc++)
                acc = __builtin_amdgcn_mfma_f32_16x16x32_bf16(a[kc], ldbf8(bp + kc * 512), acc, 0, 0, 0);
            int col = nt * 16 + lm;
            float bias = b2[col];
            #pragma unroll
            for (int r = 0; r < 4; r++)
                sA[(w * 16 + q * 4 + r) * 136 + col] = f2bf(sp2(acc[r] + bias));
        }
    }
    // stage 3: three projections (wave-private rows)
    {
        bf16x8 a3[4];
        const u16* ar = sA + (w * 16 + lm) * 136;
        #pragma unroll
        for (int kc = 0; kc < 4; kc++) a3[kc] = ldbf8(ar + kc * 32 + q * 8);
        const u16* Ps[3] = {P0, P1, P2};
        u16*       Os[3] = {O0, O1, O2};
        const int  RS[3] = {256, 256, 128};
        #pragma unroll
        for (int p = 0; p < 3; p++) {
            for (int nt = 0; nt < 8; nt++) {
                f32x4 acc = {0.f, 0.f, 0.f, 0.f};
                const u16* bp = Ps[p] + nt * 2048 + lane * 8;
                #pragma unroll
                for (int kc = 0; kc < 4; kc++)
                    acc = __builtin_amdgcn_mfma_f32_16x16x32_bf16(a3[kc], ldbf8(bp + kc * 512), acc, 0, 0, 0);
                int col = nt * 16 + lm;
                #pragma unroll
                for (int r = 0; r < 4; r++) {
                    int row = base + w * 16 + q * 4 + r;
                    if (row < NN) Os[p][(size_t)row * RS[p] + col] = f2bf(acc[r]);
                }
            }
        }
    }
}

// ---------------- global-features pre-block ----------------
__global__ __launch_bounds__(256) void gdense_kernel(
    const float* __restrict__ gf0, const float* __restrict__ gW1, const float* __restrict__ gb1,
    const float* __restrict__ gW2, const float* __restrict__ gb2,
    const float* __restrict__ emW, const float* __restrict__ emb,
    const float* __restrict__ nmW, const float* __restrict__ nmb,
    float* __restrict__ gf_pre, float* __restrict__ gfd, float* __restrict__ gfn3b)
{
    __shared__ float s_in[128], s_h1[256], s_h2[128];
    int r = blockIdx.x;
    int t = threadIdx.x;
    if (t < 128) s_in[t] = gf0[r * 128 + t];
    __syncthreads();
    {
        float acc = gb1[t];
        for (int k = 0; k < 128; k++) acc += s_in[k] * gW1[k * 256 + t];
        s_h1[t] = sp2(acc);
    }
    __syncthreads();
    if (t < 128) {
        float acc = gb2[t];
        for (int k = 0; k < 256; k++) acc += s_h1[k] * gW2[k * 128 + t];
        float v = sp2(acc);
        s_h2[t] = v; gf_pre[r * 128 + t] = v;
    }
    __syncthreads();
    if (t < 128) {
        float a1 = emb[t];
        for (int k = 0; k < 128; k++) a1 += s_h2[k] * emW[(size_t)(384 + k) * 128 + t];
        gfd[r * 128 + t] = a1;
    } else {
        int c = t - 128;
        float a2 = nmb[c];
        for (int k = 0; k < 128; k++) a2 += s_h2[k] * nmW[(size_t)(256 + k) * 128 + c];
        gfn3b[r * 128 + c] = a2;
    }
}

// ---------------- edge MLP: ef0 -> dense -> ec, ec staged into fg f-half (bf16) ----------------
__global__ __launch_bounds__(256, 3) void edge_mlp_kernel(
    const float* __restrict__ ef0,
    const u16* __restrict__ W1p, const float* __restrict__ b1,
    const u16* __restrict__ W2p, const float* __restrict__ b2,
    const u16* __restrict__ Wcp,
    u16* __restrict__ fg)
{
    __shared__ __align__(16) u16 sA[64 * 136];    // ef0 tile -> h2 -> ec
    __shared__ __align__(16) u16 sH[64 * 264];    // h1
    int tid  = threadIdx.x;
    int base = blockIdx.x * 64;
    // stage ef0 tile -> bf16
    {
        int r = tid >> 2, p = tid & 3;
        int row = base + r;
        u16* d = sA + r * 136 + p * 32;
        if (row < NE) {
            const float* s = ef0 + (size_t)row * 128 + p * 32;
            #pragma unroll
            for (int i = 0; i < 4; i++) {
                f32x4 f0 = *(const f32x4*)(s + i * 8);
                f32x4 f1 = *(const f32x4*)(s + i * 8 + 4);
                u16x8 v;
                v[0]=f2bf(f0[0]); v[1]=f2bf(f0[1]); v[2]=f2bf(f0[2]); v[3]=f2bf(f0[3]);
                v[4]=f2bf(f1[0]); v[5]=f2bf(f1[1]); v[6]=f2bf(f1[2]); v[7]=f2bf(f1[3]);
                *(u16x8*)(d + i * 8) = v;
            }
        } else {
            u16x8 z = {0,0,0,0,0,0,0,0};
            #pragma unroll
            for (int i = 0; i < 4; i++) *(u16x8*)(d + i * 8) = z;
        }
    }
    __syncthreads();
    int lane = tid & 63, w = tid >> 6, q = lane >> 4, lm = lane & 15;
    // stage 1: nt-split across waves
    {
        bf16x8 a[4][4];
        #pragma unroll
        for (int rt = 0; rt < 4; rt++)
            #pragma unroll
            for (int kc = 0; kc < 4; kc++)
                a[rt][kc] = ldbf8(sA + (rt * 16 + lm) * 136 + kc * 32 + q * 8);
        for (int nti = 0; nti < 4; nti++) {
            int nt = w * 4 + nti;
            bf16x8 bfr[4];
            #pragma unroll
            for (int kc = 0; kc < 4; kc++) bfr[kc] = ldbf8(W1p + nt * 2048 + kc * 512 + lane * 8);
            f32x4 acc[4] = {{0,0,0,0},{0,0,0,0},{0,0,0,0},{0,0,0,0}};
            #pragma unroll
            for (int kc = 0; kc < 4; kc++)
                #pragma unroll
                for (int rt = 0; rt < 4; rt++)
                    acc[rt] = __builtin_amdgcn_mfma_f32_16x16x32_bf16(a[rt][kc], bfr[kc], acc[rt], 0, 0, 0);
            int col = nt * 16 + lm;
            float bias = b1[col];
            #pragma unroll
            for (int rt = 0; rt < 4; rt++)
                #pragma unroll
                for (int r = 0; r < 4; r++)
                    sH[(rt * 16 + q * 4 + r) * 264 + col] = f2bf(sp2(acc[rt][r] + bias));
        }
    }
    __syncthreads();
    // stage 2: row-split
    {
        bf16x8 a[8];
        const u16* ar = sH + (w * 16 + lm) * 264;
        #pragma unroll
        for (int kc = 0; kc < 8; kc++) a[kc] = ldbf8(ar + kc * 32 + q * 8);
        #pragma unroll 2
        for (int nt = 0; nt < 8; nt++) {
            f32x4 acc = {0.f, 0.f, 0.f, 0.f};
            const u16* bp = W2p + nt * 4096 + lane * 8;
            #pragma unroll
            for (int kc = 0; kc < 8; kc++)
                acc = __builtin_amdgcn_mfma_f32_16x16x32_bf16(a[kc], ldbf8(bp + kc * 512), acc, 0, 0, 0);
            int col = nt * 16 + lm;
            float bias = b2[col];
            #pragma unroll
            for (int r = 0; r < 4; r++)
                sA[(w * 16 + q * 4 + r) * 136 + col] = f2bf(sp2(acc[r] + bias));
        }
    }
    // stage 3: ec = h2 @ Wc -> back into sA (frags read before overwrite, wave-private)
    {
        bf16x8 a3[4];
        const u16* ar = sA + (w * 16 + lm) * 136;
        #pragma unroll
        for (int kc = 0; kc < 4; kc++) a3[kc] = ldbf8(ar + kc * 32 + q * 8);
        #pragma unroll 2
        for (int nt = 0; nt < 8; nt++) {
            f32x4 acc = {0.f, 0.f, 0.f, 0.f};
            const u16* bp = Wcp + nt * 2048 + lane * 8;
            #pragma unroll
            for (int kc = 0; kc < 4; kc++)
                acc = __builtin_amdgcn_mfma_f32_16x16x32_bf16(a3[kc], ldbf8(bp + kc * 512), acc, 0, 0, 0);
            int col = nt * 16 + lm;
            #pragma unroll
            for (int r = 0; r < 4; r++)
                sA[(w * 16 + q * 4 + r) * 136 + col] = f2bf(acc[r]);
        }
    }
    __syncthreads();
    // write ec tile to fg f-half (coalesced 256B rows); edge_compute reads then overwrites in-place
    {
        int r = tid >> 2, p = tid & 3;
        int row = base + r;
        if (row < NE) {
            u16* dptr = fg + (size_t)row * 128 + p * 32;
            const u16* sptr = sA + r * 136 + p * 32;
            #pragma unroll
            for (int i = 0; i < 4; i++) *(u16x8*)(dptr + i * 8) = *(const u16x8*)(sptr + i * 8);
        }
    }
}

// ---------------- edge compute: pure gather + edge update streams (NO LDS, NO atomics, NO barriers) ----------------
// 16-lane group per edge; grid-stride. Ablates the s_em/em32 path entirely -> em_reduce_kernel.
__global__ __launch_bounds__(256, 6) void edge_compute_kernel(
    const float* __restrict__ ef0, const int* __restrict__ ei, const int* __restrict__ batch,
    const u16* __restrict__ nfab, const float* __restrict__ gfd,
    float* __restrict__ ef_out, u16* __restrict__ fg)
{
    int tid = threadIdx.x;
    int grp0 = blockIdx.x * 16 + (tid >> 4);
    int ci  = (tid & 15) * 8;
    int stride = gridDim.x * 16;
    for (int e = grp0; e < NE; e += stride) {
        int s = ei[e], d = ei[NE + e];
        // stream loads first (likely HBM), then gathers (likely L2/L3)
        u16x8 ecv = *(const u16x8*)(fg + (size_t)e * 128 + ci);
        f32x4 e0a = *(const f32x4*)(ef0 + (size_t)e * 128 + ci);
        f32x4 e0b = *(const f32x4*)(ef0 + (size_t)e * 128 + ci + 4);
        u16x8 va  = *(const u16x8*)(nfab + (size_t)s * 256 + ci);
        u16x8 vbs = *(const u16x8*)(nfab + (size_t)s * 256 + 128 + ci);
        u16x8 vad = *(const u16x8*)(nfab + (size_t)d * 256 + ci);
        u16x8 vbd = *(const u16x8*)(nfab + (size_t)d * 256 + 128 + ci);
        int gbf = batch[s], gbb = batch[d];
        f32x4 gfa = *(const f32x4*)(gfd + gbf * 128 + ci);
        f32x4 gfa2 = *(const f32x4*)(gfd + gbf * 128 + ci + 4);
        f32x4 gfb = *(const f32x4*)(gfd + gbb * 128 + ci);
        f32x4 gfb2 = *(const f32x4*)(gfd + gbb * 128 + ci + 4);
        u16x8 fv, gv;
        f32x4 oa, ob;
        #pragma unroll
        for (int i = 0; i < 8; i++) {
            float ec = b2f(ecv[i]);
            float gf_f = (i < 4) ? gfa[i & 3] : gfa2[i & 3];
            float gf_b = (i < 4) ? gfb[i & 3] : gfb2[i & 3];
            float f = b2f(va[i])  + b2f(vbd[i]) + ec + gf_f;
            float g = b2f(vad[i]) + b2f(vbs[i]) + ec + gf_b;
            float o = 0.5f * (f + g) + ((i < 4) ? e0a[i & 3] : e0b[i & 3]);
            if (i < 4) oa[i & 3] = o; else ob[i & 3] = o;
            fv[i] = f2bf(f); gv[i] = f2bf(g);
        }
        float* eop = ef_out + (size_t)e * 128 + ci;
        *(f32x4*)(eop)     = oa;
        *(f32x4*)(eop + 4) = ob;
        *(u16x8*)(fg + (size_t)e * 128 + ci) = fv;                // overwrite ec in place
        *(u16x8*)(fg + (size_t)(NE + e) * 128 + ci) = gv;
    }
}

// ---------------- em reduce: sequential sweep over fg rows keyed by gbk ----------------
__global__ __launch_bounds__(256, 8) void em_reduce_kernel(
    const u16* __restrict__ fg, const u8* __restrict__ gbk, float* __restrict__ em32)
{
    __shared__ float s_em[16 * 136];
    int tid = threadIdx.x;
    for (int i = tid; i < 16 * 136; i += 256) s_em[i] = 0.f;
    __syncthreads();
    int el0 = tid >> 4, cch = tid & 15, ci = cch * 8, rot = cch >> 2;
    int stride = gridDim.x * 16;
    for (int r = blockIdx.x * 16 + el0; r < 2 * NE; r += stride) {
        u16x8 v = *(const u16x8*)(fg + (size_t)r * 128 + ci);
        int g = gbk[r];
        #pragma unroll
        for (int i = 0; i < 8; i++) {
            int jj = (i + rot) & 7;
            atomicAdd(&s_em[g * 136 + ci + jj], b2f(v[jj]));
        }
    }
    __syncthreads();
    float* dstm = em32 + (size_t)(blockIdx.x & (EM_REP - 1)) * 2048;
    for (int i = tid; i < 2048; i += 256) {
        int g = i >> 7, c = i & 127;
        unsafeAtomicAdd(&dstm[i], s_em[g * 136 + c]);
    }
}

// ---------------- node update: CSR gather + efm @ Wn2 via MFMA ----------------
__global__ __launch_bounds__(256) void node_update_kernel(
    const float* __restrict__ nf0, const u16* __restrict__ nfn1,
    const u16* __restrict__ fg, const u32* __restrict__ off,
    const u32* __restrict__ node_cnt, const u32* __restrict__ list,
    const u16* __restrict__ Wn2p, const float* __restrict__ gfn3b, const int* __restrict__ batch,
    float* __restrict__ nf_out, float* __restrict__ nm_acc, u32* __restrict__ nm_cnt)
{
    __shared__ __align__(16) u16 sE[64 * 136];
    __shared__ float s_nm[2048];
    __shared__ u32 s_ncnt[16];
    int tid = threadIdx.x;
    for (int i = tid; i < 2048; i += 256) s_nm[i] = 0.f;
    if (tid < 16) s_ncnt[tid] = 0;
    __syncthreads();
    int base = blockIdx.x * 64;
    {
        int r = tid >> 2, p = tid & 3;
        int n = base + r;
        u16* d = sE + r * 136 + p * 32;
        if (n < NN) {
            u32 o = off[n], c = node_cnt[n];
            float acc[32];
            #pragma unroll
            for (int i = 0; i < 32; i++) acc[i] = 0.f;
            u32 row = (c > 0) ? list[o] : 0;            // prefetch next row index
            for (u32 j = 0; j < c; j++) {
                u32 rcur = row;
                if (j + 1 < c) row = list[o + j + 1];
                const u16* pr = fg + (size_t)rcur * 128 + p * 32;
                #pragma unroll
                for (int i2 = 0; i2 < 4; i2++) {
                    u16x8 v = *(const u16x8*)(pr + i2 * 8);
                    #pragma unroll
                    for (int jj = 0; jj < 8; jj++) acc[i2 * 8 + jj] += b2f(v[jj]);
                }
            }
            float inv = 1.f / fmaxf((float)c, 1.f);
            #pragma unroll
            for (int i2 = 0; i2 < 4; i2++) {
                u16x8 ov;
                #pragma unroll
                for (int jj = 0; jj < 8; jj++) ov[jj] = f2bf(acc[i2 * 8 + jj] * inv);
                *(u16x8*)(d + i2 * 8) = ov;
            }
            if (p == 0) atomicAdd(&s_ncnt[batch[n]], 1u);
        } else {
            u16x8 z = {0,0,0,0,0,0,0,0};
            #pragma unroll
            for (int i = 0; i < 4; i++) *(u16x8*)(d + i * 8) = z;
        }
    }
    __syncthreads();
    int lane = tid & 63, w = tid >> 6, q = lane >> 4, lm = lane & 15;
    int rows[4]; bool ok[4]; int gg[4];
    #pragma unroll
    for (int r = 0; r < 4; r++) {
        rows[r] = base + w * 16 + q * 4 + r;
        ok[r] = rows[r] < NN;
        gg[r] = ok[r] ? batch[rows[r]] : 0;
    }
    bf16x8 a[4];
    const u16* ar = sE + (w * 16 + lm) * 136;
    #pragma unroll
    for (int kc = 0; kc < 4; kc++) a[kc] = ldbf8(ar + kc * 32 + q * 8);
    for (int nt = 0; nt < 8; nt++) {
        f32x4 acc = {0.f, 0.f, 0.f, 0.f};
        const u16* bp = Wn2p + nt * 2048 + lane * 8;
        #pragma unroll
        for (int kc = 0; kc < 4; kc++)
            acc = __builtin_amdgcn_mfma_f32_16x16x32_bf16(a[kc], ldbf8(bp + kc * 512), acc, 0, 0, 0);
        int col = nt * 16 + lm;
        #pragma unroll
        for (int r = 0; r < 4; r++) {
            if (ok[r]) {
                size_t idx = (size_t)rows[r] * 128 + col;
                float upd = acc[r] + b2f(nfn1[idx]) + gfn3b[gg[r] * 128 + col];
                nf_out[idx] = upd + nf0[idx];
                atomicAdd(&s_nm[gg[r] * 128 + col], upd);
            }
        }
    }
    __syncthreads();
    for (int g = 0; g < 16; g++) {
        u32 c = s_ncnt[g];
        if (c) {
            if (tid < 128) unsafeAtomicAdd(&nm_acc[g * 128 + tid], s_nm[g * 128 + tid]);
            if (tid == 0) atomicAdd(&nm_cnt[g], c);
        }
    }
}

// ---------------- global update: one block per graph ----------------
__global__ __launch_bounds__(256) void global_update_kernel(
    const float* __restrict__ gf0, const float* __restrict__ gf_pre,
    const float* __restrict__ em32, const u32* __restrict__ ecnt,
    const float* __restrict__ nm_acc, const u32* __restrict__ nm_cnt,
    const float* __restrict__ gmW, const float* __restrict__ gmb,
    float* __restrict__ gf_out)
{
    __shared__ float s_cat[384];
    int g = blockIdx.x;
    int tid = threadIdx.x;
    for (int i = tid; i < 384; i += 256) {
        int seg = i >> 7, c = i & 127;
        float v;
        if (seg == 0) {
            float s = 0.f;
            for (int r = 0; r < EM_REP; r++) s += em32[(size_t)r * 2048 + g * 128 + c];
            v = s / fmaxf((float)ecnt[g], 1.f);
        } else if (seg == 1) {
            v = nm_acc[g * 128 + c] / fmaxf((float)nm_cnt[g], 1.f);
        } else {
            v = gf_pre[g * 128 + c];
        }
        s_cat[i] = v;
    }
    __syncthreads();
    for (int c = tid; c < 128; c += 256) {
        float acc = gmb[c];
        for (int k = 0; k < 384; k++) acc += s_cat[k] * gmW[k * 128 + c];
        gf_out[g * 128 + c] = acc + gf0[g * 128 + c];
    }
}

// ---------------- launcher ----------------
extern "C" void kernel_launch(void* const* d_in, const int* in_sizes, int n_in,
                              void* d_out, int out_size, void* d_ws, size_t ws_size,
                              hipStream_t stream) {
    const float* nf0 = (const float*)d_in[0];
    const int*   ei  = (const int*)d_in[1];
    const float* ef0 = (const float*)d_in[2];
    const float* gf0 = (const float*)d_in[3];
    const int* batch = (const int*)d_in[4];
    const float *eW1 = (const float*)d_in[5],  *eb1 = (const float*)d_in[6];
    const float *eW2 = (const float*)d_in[7],  *eb2 = (const float*)d_in[8];
    const float *nW1 = (const float*)d_in[9],  *nb1 = (const float*)d_in[10];
    const float *nW2 = (const float*)d_in[11], *nb2 = (const float*)d_in[12];
    const float *gW1 = (const float*)d_in[13], *gb1 = (const float*)d_in[14];
    const float *gW2 = (const float*)d_in[15], *gb2 = (const float*)d_in[16];
    const float *emW = (const float*)d_in[17], *emb = (const float*)d_in[18];
    const float *nmW = (const float*)d_in[19], *nmb = (const float*)d_in[20];
    const float *gmW = (const float*)d_in[21], *gmb = (const float*)d_in[22];

    if (ws_size < WS_NEED) {
        fprintf(stderr, "kernel_launch: ws too small: %zu < %zu\n", ws_size, WS_NEED);
        return;
    }
    char* ws = (char*)d_ws;
    u16* nfab   = (u16*)(ws + OFF_NFA);   // [NN,256] interleaved nfa|nfb
    u16* nfn1   = (u16*)(ws + OFF_NFN1);
    u16* fg     = (u16*)(ws + OFF_FG);
    u32* list   = (u32*)(ws + OFF_LIST);
    u32* ncnt   = (u32*)(ws + OFF_NCNT);
    u32* ecnt   = (u32*)(ws + OFF_ECNT);
    float* em32 = (float*)(ws + OFF_EM32);
    u32* offa   = (u32*)(ws + OFF_OFFA);
    u32* curs   = (u32*)(ws + OFF_CURS);
    u32* bsum   = (u32*)(ws + OFF_BSUM);
    u16* pk     = (u16*)(ws + OFF_PACK);
    u8*  gbk    = (u8*)(ws + OFF_GBK);

    float* nf_out = (float*)d_out;
    float* ef_out = nf_out + (size_t)NN * 128;
    float* gf_out = ef_out + (size_t)NE * 128;

    hipMemsetAsync(ws + OFF_NCNT, 0, ZERO_SZ, stream);

    pack_kernel<<<832, 256, 0, stream>>>(eW1, eW2, nW1, nW2, emW, nmW, pk);
    gdense_kernel<<<16, 256, 0, stream>>>(gf0, gW1, gb1, gW2, gb2, emW, emb, nmW, nmb,
                                          (float*)(ws + OFF_GFP), (float*)(ws + OFF_GFD),
                                          (float*)(ws + OFF_GFN3));
    deg_kernel<<<512, 256, 0, stream>>>(ei, batch, ncnt, ecnt, gbk);
    scan1_kernel<<<NB_SCAN, 256, 0, stream>>>(ncnt, bsum);
    scan2_kernel<<<1, 256, 0, stream>>>(bsum);
    scan3_kernel<<<NB_SCAN, 256, 0, stream>>>(ncnt, bsum, offa, curs);
    fill_kernel<<<512, 256, 0, stream>>>(ei, curs, list);
    mlp_node_kernel<<<(NN + 63) / 64, 256, 0, stream>>>(
        nf0, pk + 65536, nb1, pk + 98304, nb2,
        pk + 131072, pk + 147456, pk + 180224, nfab, nfab + 128, nfn1);
    edge_mlp_kernel<<<(NE + 63) / 64, 256, 0, stream>>>(
        ef0, pk + 0, eb1, pk + 32768, eb2, pk + 163840, fg);
    edge_compute_kernel<<<1536, 256, 0, stream>>>(
        ef0, ei, batch, nfab, (const float*)(ws + OFF_GFD),
        ef_out, fg);
    em_reduce_kernel<<<1024, 256, 0, stream>>>(
        fg, gbk, em32);
    node_update_kernel<<<(NN + 63) / 64, 256, 0, stream>>>(
        nf0, nfn1, fg, offa, ncnt, list,
        pk + 196608, (const float*)(ws + OFF_GFN3), batch,
        nf_out, (float*)(ws + OFF_NMA), (u32*)(ws + OFF_NMC));
    global_update_kernel<<<16, 256, 0, stream>>>(
        gf0, (const float*)(ws + OFF_GFP),
        em32, ecnt,
        (const float*)(ws + OFF_NMA), (const u32*)(ws + OFF_NMC),
        gmW, gmb, gf_out);
}

// Round 6
// 726.255 us; speedup vs baseline: 1.4089x; 1.4089x over previous
//
#include <hip/hip_runtime.h>
#include <cstdio>

using u16 = unsigned short;
using u32 = unsigned int;
using u8  = unsigned char;

typedef __attribute__((ext_vector_type(8))) u16    u16x8;
typedef __attribute__((ext_vector_type(8))) __bf16 bf16x8;
typedef __attribute__((ext_vector_type(4))) float  f32x4;

constexpr int NN = 50000;   // nodes
constexpr int NE = 250000;  // edges
constexpr int EM_REP = 32;  // em replica count
constexpr int NB_SCAN = (NN + 255) / 256;  // 196
constexpr int EMR_GRID = 512;              // em_reduce blocks
constexpr int EMR_STEPS = (2 * NE) / 32;   // 15625 row-steps of 32

// ---------------- ws layout (bytes) ----------------
constexpr size_t OFF_NFA  = 0;                                   // bf16 [NN,256] nfab (nfa cols 0-127, nfb cols 128-255)
constexpr size_t OFF_NFB  = OFF_NFA  + (size_t)NN*128*2;         // (second half of nfab)
constexpr size_t OFF_NFN1 = OFF_NFB  + (size_t)NN*128*2;         // bf16 [NN,128] nf_dense @ Wn1
constexpr size_t OFF_FG   = OFF_NFN1 + (size_t)NN*128*2;         // bf16 [2E,128] f rows then g rows (f-half doubles as ec staging)
constexpr size_t OFF_LIST = OFF_FG   + (size_t)2*NE*128*2;       // u32 [2E] CSR lists
// ---- zeroed region ----
constexpr size_t OFF_NCNT = OFF_LIST + (size_t)2*NE*4;           // u32 [NN] pad 200704
constexpr size_t OFF_ECNT = OFF_NCNT + 200704;                   // u32 [16] pad 256
constexpr size_t OFF_EM32 = OFF_ECNT + 256;                      // f32 [EM_REP,2048]
constexpr size_t OFF_NMA  = OFF_EM32 + (size_t)EM_REP*2048*4;    // f32 [2048]
constexpr size_t OFF_NMC  = OFF_NMA  + 8192;                     // u32 [16] pad 256
constexpr size_t ZERO_SZ  = (OFF_NMC + 256) - OFF_NCNT;
// ---- end zeroed ----
constexpr size_t OFF_OFFA = OFF_NMC  + 256;                      // u32 [NN] CSR offsets (kept)
constexpr size_t OFF_CURS = OFF_OFFA + 200704;                   // u32 [NN] cursors (consumed)
constexpr size_t OFF_BSUM = OFF_CURS + 200704;                   // u32 [196] pad 1024
constexpr size_t OFF_GFP  = OFF_BSUM + 1024;                     // f32 [16,128] gf_pre
constexpr size_t OFF_GFD  = OFF_GFP  + 8192;                     // f32 gf_pre@Wd+emb
constexpr size_t OFF_GFN3 = OFF_GFD  + 8192;                     // f32 gf_pre@Wn3+nmb
constexpr size_t OFF_PACK = OFF_GFN3 + 8192;                     // bf16 packed weights 212992
constexpr size_t OFF_GBK  = OFF_PACK + (size_t)212992*2;         // u8 [2E] per-row graph key (f rows: batch[src], g rows: batch[dst])
constexpr size_t WS_NEED  = OFF_GBK + (size_t)2*NE;

// ---------------- helpers ----------------
static __device__ __forceinline__ float b2f(u16 u) {
    union { u32 u; float f; } x; x.u = ((u32)u) << 16; return x.f;
}
static __device__ __forceinline__ u16 f2bf(float f) {
    union { float f; u32 u; } x; x.f = f;
    u32 r = x.u + 0x7fffu + ((x.u >> 16) & 1u);
    return (u16)(r >> 16);
}
static __device__ __forceinline__ float sp2(float x) {
    return fmaxf(x, 0.f) + __logf(1.f + __expf(-fabsf(x))) - 0.6931471805599453f;
}
static __device__ __forceinline__ bf16x8 ldbf8(const u16* p) {
    return __builtin_bit_cast(bf16x8, *(const u16x8*)p);
}

// ---------------- weight pre-swizzle (fp32 -> bf16 B-fragment order) ----------------
__global__ __launch_bounds__(256) void pack_kernel(
    const float* __restrict__ eW1, const float* __restrict__ eW2,
    const float* __restrict__ nW1, const float* __restrict__ nW2,
    const float* __restrict__ emW, const float* __restrict__ nmW,
    u16* __restrict__ dst)
{
    int gid = blockIdx.x * 256 + threadIdx.x;
    if (gid >= 212992) return;
    const float* src; int rowOff, Nsrc, KC, local;
    if      (gid <  32768) { src=eW1; rowOff=0;   Nsrc=256; KC=4; local=gid; }
    else if (gid <  65536) { src=eW2; rowOff=0;   Nsrc=128; KC=8; local=gid-32768; }
    else if (gid <  98304) { src=nW1; rowOff=0;   Nsrc=256; KC=4; local=gid-65536; }
    else if (gid < 131072) { src=nW2; rowOff=0;   Nsrc=128; KC=8; local=gid-98304; }
    else if (gid < 147456) { src=emW; rowOff=0;   Nsrc=128; KC=4; local=gid-131072; } // Wa
    else if (gid < 163840) { src=emW; rowOff=128; Nsrc=128; KC=4; local=gid-147456; } // Wb
    else if (gid < 180224) { src=emW; rowOff=256; Nsrc=128; KC=4; local=gid-163840; } // Wc
    else if (gid < 196608) { src=nmW; rowOff=0;   Nsrc=128; KC=4; local=gid-180224; } // Wn1
    else                   { src=nmW; rowOff=128; Nsrc=128; KC=4; local=gid-196608; } // Wn2
    int j    = local & 7;
    int lane = (local >> 3) & 63;
    int t    = local >> 9;
    int kc   = t & (KC - 1);
    int nt   = t >> (KC == 8 ? 3 : 2);
    int k = kc * 32 + ((lane >> 4) << 3) + j;
    int n = nt * 16 + (lane & 15);
    dst[gid] = f2bf(src[(size_t)(rowOff + k) * Nsrc + n]);
}

// ---------------- degree / per-graph directed-edge count / per-row graph key ----------------
__global__ __launch_bounds__(256) void deg_kernel(
    const int* __restrict__ ei, const int* __restrict__ batch,
    u32* __restrict__ node_cnt, u32* __restrict__ ecnt, u8* __restrict__ gbk)
{
    __shared__ u32 s_h[16];
    if (threadIdx.x < 16) s_h[threadIdx.x] = 0;
    __syncthreads();
    for (int e = blockIdx.x * 256 + threadIdx.x; e < NE; e += gridDim.x * 256) {
        int s = ei[e], d = ei[NE + e];
        int bs = batch[s], bd = batch[d];
        atomicAdd(&node_cnt[d], 1u);
        atomicAdd(&node_cnt[s], 1u);
        atomicAdd(&s_h[bs], 1u);
        atomicAdd(&s_h[bd], 1u);
        gbk[e]      = (u8)bs;   // f row e keyed by batch[src]
        gbk[NE + e] = (u8)bd;   // g row e keyed by batch[dst]
    }
    __syncthreads();
    if (threadIdx.x < 16 && s_h[threadIdx.x]) atomicAdd(&ecnt[threadIdx.x], s_h[threadIdx.x]);
}

// ---------------- CSR scan (3 passes) + fill ----------------
__global__ __launch_bounds__(256) void scan1_kernel(const u32* __restrict__ ncnt, u32* __restrict__ bsum) {
    __shared__ u32 red[256];
    int i = blockIdx.x * 256 + threadIdx.x;
    red[threadIdx.x] = (i < NN) ? ncnt[i] : 0;
    __syncthreads();
    for (int s = 128; s > 0; s >>= 1) {
        if (threadIdx.x < s) red[threadIdx.x] += red[threadIdx.x + s];
        __syncthreads();
    }
    if (threadIdx.x == 0) bsum[blockIdx.x] = red[0];
}
// parallel exclusive scan over NB_SCAN block sums (one 256-thread block)
__global__ __launch_bounds__(256) void scan2_kernel(u32* __restrict__ bsum) {
    __shared__ u32 sc[256];
    int tid = threadIdx.x;
    u32 v = (tid < NB_SCAN) ? bsum[tid] : 0;
    sc[tid] = v;
    __syncthreads();
    for (int d = 1; d < 256; d <<= 1) {
        u32 t = (tid >= d) ? sc[tid - d] : 0;
        __syncthreads();
        sc[tid] += t;
        __syncthreads();
    }
    if (tid < NB_SCAN) bsum[tid] = sc[tid] - v;
}
__global__ __launch_bounds__(256) void scan3_kernel(
    const u32* __restrict__ ncnt, const u32* __restrict__ boff,
    u32* __restrict__ off, u32* __restrict__ cursor)
{
    __shared__ u32 sc[256];
    int i = blockIdx.x * 256 + threadIdx.x;
    u32 v = (i < NN) ? ncnt[i] : 0;
    sc[threadIdx.x] = v;
    __syncthreads();
    for (int d = 1; d < 256; d <<= 1) {
        u32 t = (threadIdx.x >= d) ? sc[threadIdx.x - d] : 0;
        __syncthreads();
        sc[threadIdx.x] += t;
        __syncthreads();
    }
    u32 excl = sc[threadIdx.x] - v + boff[blockIdx.x];
    if (i < NN) { off[i] = excl; cursor[i] = excl; }
}
__global__ __launch_bounds__(256) void fill_kernel(
    const int* __restrict__ ei, u32* __restrict__ cursor, u32* __restrict__ list)
{
    for (int e = blockIdx.x * 256 + threadIdx.x; e < NE; e += gridDim.x * 256) {
        int s = ei[e], d = ei[NE + e];
        u32 p1 = atomicAdd(&cursor[d], 1u); list[p1] = (u32)e;        // f row -> node d
        u32 p2 = atomicAdd(&cursor[s], 1u); list[p2] = (u32)(NE + e); // g row -> node s
    }
}

// ---------------- node MLP (full-width, nt-split stage1) + 3 projections ----------------
// O0 = nfab (cols 0-127, row stride 256), O1 = nfab+128 (cols 128-255), O2 = nfn1 (stride 128)
__global__ __launch_bounds__(256, 3) void mlp_node_kernel(
    const float* __restrict__ in,
    const u16* __restrict__ W1p, const float* __restrict__ b1,
    const u16* __restrict__ W2p, const float* __restrict__ b2,
    const u16* __restrict__ P0, const u16* __restrict__ P1, const u16* __restrict__ P2,
    u16* __restrict__ O0, u16* __restrict__ O1, u16* __restrict__ O2)
{
    __shared__ __align__(16) u16 sA[64 * 136];   // input tile -> h2
    __shared__ __align__(16) u16 sH[64 * 264];   // h1 tile
    int tid  = threadIdx.x;
    int base = blockIdx.x * 64;
    {
        int r = tid >> 2, p = tid & 3;
        int row = base + r;
        u16* d = sA + r * 136 + p * 32;
        if (row < NN) {
            const float* s = in + (size_t)row * 128 + p * 32;
            #pragma unroll
            for (int i = 0; i < 4; i++) {
                f32x4 f0 = *(const f32x4*)(s + i * 8);
                f32x4 f1 = *(const f32x4*)(s + i * 8 + 4);
                u16x8 v;
                v[0]=f2bf(f0[0]); v[1]=f2bf(f0[1]); v[2]=f2bf(f0[2]); v[3]=f2bf(f0[3]);
                v[4]=f2bf(f1[0]); v[5]=f2bf(f1[1]); v[6]=f2bf(f1[2]); v[7]=f2bf(f1[3]);
                *(u16x8*)(d + i * 8) = v;
            }
        } else {
            u16x8 z = {0,0,0,0,0,0,0,0};
            #pragma unroll
            for (int i = 0; i < 4; i++) *(u16x8*)(d + i * 8) = z;
        }
    }
    __syncthreads();
    int lane = tid & 63, w = tid >> 6, q = lane >> 4, lm = lane & 15;
    // stage 1: nt-split across waves
    {
        bf16x8 a[4][4];
        #pragma unroll
        for (int rt = 0; rt < 4; rt++)
            #pragma unroll
            for (int kc = 0; kc < 4; kc++)
                a[rt][kc] = ldbf8(sA + (rt * 16 + lm) * 136 + kc * 32 + q * 8);
        for (int nti = 0; nti < 4; nti++) {
            int nt = w * 4 + nti;
            bf16x8 bfr[4];
            #pragma unroll
            for (int kc = 0; kc < 4; kc++) bfr[kc] = ldbf8(W1p + nt * 2048 + kc * 512 + lane * 8);
            f32x4 acc[4] = {{0,0,0,0},{0,0,0,0},{0,0,0,0},{0,0,0,0}};
            #pragma unroll
            for (int kc = 0; kc < 4; kc++)
                #pragma unroll
                for (int rt = 0; rt < 4; rt++)
                    acc[rt] = __builtin_amdgcn_mfma_f32_16x16x32_bf16(a[rt][kc], bfr[kc], acc[rt], 0, 0, 0);
            int col = nt * 16 + lm;
            float bias = b1[col];
            #pragma unroll
            for (int rt = 0; rt < 4; rt++)
                #pragma unroll
                for (int r = 0; r < 4; r++)
                    sH[(rt * 16 + q * 4 + r) * 264 + col] = f2bf(sp2(acc[rt][r] + bias));
        }
    }
    __syncthreads();
    // stage 2: row-split
    {
        bf16x8 a[8];
        const u16* ar = sH + (w * 16 + lm) * 264;
        #pragma unroll
        for (int kc = 0; kc < 8; kc++) a[kc] = ldbf8(ar + kc * 32 + q * 8);
        for (int nt = 0; nt < 8; nt++) {
            f32x4 acc = {0.f, 0.f, 0.f, 0.f};
            const u16* bp = W2p + nt * 4096 + lane * 8;
            #pragma unroll
            for (int kc = 0; kc < 8; kc++)
                acc = __builtin_amdgcn_mfma_f32_16x16x32_bf16(a[kc], ldbf8(bp + kc * 512), acc, 0, 0, 0);
            int col = nt * 16 + lm;
            float bias = b2[col];
            #pragma unroll
            for (int r = 0; r < 4; r++)
                sA[(w * 16 + q * 4 + r) * 136 + col] = f2bf(sp2(acc[r] + bias));
        }
    }
    // stage 3: three projections (wave-private rows)
    {
        bf16x8 a3[4];
        const u16* ar = sA + (w * 16 + lm) * 136;
        #pragma unroll
        for (int kc = 0; kc < 4; kc++) a3[kc] = ldbf8(ar + kc * 32 + q * 8);
        const u16* Ps[3] = {P0, P1, P2};
        u16*       Os[3] = {O0, O1, O2};
        const int  RS[3] = {256, 256, 128};
        #pragma unroll
        for (int p = 0; p < 3; p++) {
            for (int nt = 0; nt < 8; nt++) {
                f32x4 acc = {0.f, 0.f, 0.f, 0.f};
                const u16* bp = Ps[p] + nt * 2048 + lane * 8;
                #pragma unroll
                for (int kc = 0; kc < 4; kc++)
                    acc = __builtin_amdgcn_mfma_f32_16x16x32_bf16(a3[kc], ldbf8(bp + kc * 512), acc, 0, 0, 0);
                int col = nt * 16 + lm;
                #pragma unroll
                for (int r = 0; r < 4; r++) {
                    int row = base + w * 16 + q * 4 + r;
                    if (row < NN) Os[p][(size_t)row * RS[p] + col] = f2bf(acc[r]);
                }
            }
        }
    }
}

// ---------------- global-features pre-block ----------------
__global__ __launch_bounds__(256) void gdense_kernel(
    const float* __restrict__ gf0, const float* __restrict__ gW1, const float* __restrict__ gb1,
    const float* __restrict__ gW2, const float* __restrict__ gb2,
    const float* __restrict__ emW, const float* __restrict__ emb,
    const float* __restrict__ nmW, const float* __restrict__ nmb,
    float* __restrict__ gf_pre, float* __restrict__ gfd, float* __restrict__ gfn3b)
{
    __shared__ float s_in[128], s_h1[256], s_h2[128];
    int r = blockIdx.x;
    int t = threadIdx.x;
    if (t < 128) s_in[t] = gf0[r * 128 + t];
    __syncthreads();
    {
        float acc = gb1[t];
        for (int k = 0; k < 128; k++) acc += s_in[k] * gW1[k * 256 + t];
        s_h1[t] = sp2(acc);
    }
    __syncthreads();
    if (t < 128) {
        float acc = gb2[t];
        for (int k = 0; k < 256; k++) acc += s_h1[k] * gW2[k * 128 + t];
        float v = sp2(acc);
        s_h2[t] = v; gf_pre[r * 128 + t] = v;
    }
    __syncthreads();
    if (t < 128) {
        float a1 = emb[t];
        for (int k = 0; k < 128; k++) a1 += s_h2[k] * emW[(size_t)(384 + k) * 128 + t];
        gfd[r * 128 + t] = a1;
    } else {
        int c = t - 128;
        float a2 = nmb[c];
        for (int k = 0; k < 128; k++) a2 += s_h2[k] * nmW[(size_t)(256 + k) * 128 + c];
        gfn3b[r * 128 + c] = a2;
    }
}

// ---------------- edge MLP: ef0 -> dense -> ec, ec staged into fg f-half (bf16) ----------------
__global__ __launch_bounds__(256, 3) void edge_mlp_kernel(
    const float* __restrict__ ef0,
    const u16* __restrict__ W1p, const float* __restrict__ b1,
    const u16* __restrict__ W2p, const float* __restrict__ b2,
    const u16* __restrict__ Wcp,
    u16* __restrict__ fg)
{
    __shared__ __align__(16) u16 sA[64 * 136];    // ef0 tile -> h2 -> ec
    __shared__ __align__(16) u16 sH[64 * 264];    // h1
    int tid  = threadIdx.x;
    int base = blockIdx.x * 64;
    // stage ef0 tile -> bf16
    {
        int r = tid >> 2, p = tid & 3;
        int row = base + r;
        u16* d = sA + r * 136 + p * 32;
        if (row < NE) {
            const float* s = ef0 + (size_t)row * 128 + p * 32;
            #pragma unroll
            for (int i = 0; i < 4; i++) {
                f32x4 f0 = *(const f32x4*)(s + i * 8);
                f32x4 f1 = *(const f32x4*)(s + i * 8 + 4);
                u16x8 v;
                v[0]=f2bf(f0[0]); v[1]=f2bf(f0[1]); v[2]=f2bf(f0[2]); v[3]=f2bf(f0[3]);
                v[4]=f2bf(f1[0]); v[5]=f2bf(f1[1]); v[6]=f2bf(f1[2]); v[7]=f2bf(f1[3]);
                *(u16x8*)(d + i * 8) = v;
            }
        } else {
            u16x8 z = {0,0,0,0,0,0,0,0};
            #pragma unroll
            for (int i = 0; i < 4; i++) *(u16x8*)(d + i * 8) = z;
        }
    }
    __syncthreads();
    int lane = tid & 63, w = tid >> 6, q = lane >> 4, lm = lane & 15;
    // stage 1: nt-split across waves
    {
        bf16x8 a[4][4];
        #pragma unroll
        for (int rt = 0; rt < 4; rt++)
            #pragma unroll
            for (int kc = 0; kc < 4; kc++)
                a[rt][kc] = ldbf8(sA + (rt * 16 + lm) * 136 + kc * 32 + q * 8);
        for (int nti = 0; nti < 4; nti++) {
            int nt = w * 4 + nti;
            bf16x8 bfr[4];
            #pragma unroll
            for (int kc = 0; kc < 4; kc++) bfr[kc] = ldbf8(W1p + nt * 2048 + kc * 512 + lane * 8);
            f32x4 acc[4] = {{0,0,0,0},{0,0,0,0},{0,0,0,0},{0,0,0,0}};
            #pragma unroll
            for (int kc = 0; kc < 4; kc++)
                #pragma unroll
                for (int rt = 0; rt < 4; rt++)
                    acc[rt] = __builtin_amdgcn_mfma_f32_16x16x32_bf16(a[rt][kc], bfr[kc], acc[rt], 0, 0, 0);
            int col = nt * 16 + lm;
            float bias = b1[col];
            #pragma unroll
            for (int rt = 0; rt < 4; rt++)
                #pragma unroll
                for (int r = 0; r < 4; r++)
                    sH[(rt * 16 + q * 4 + r) * 264 + col] = f2bf(sp2(acc[rt][r] + bias));
        }
    }
    __syncthreads();
    // stage 2: row-split
    {
        bf16x8 a[8];
        const u16* ar = sH + (w * 16 + lm) * 264;
        #pragma unroll
        for (int kc = 0; kc < 8; kc++) a[kc] = ldbf8(ar + kc * 32 + q * 8);
        #pragma unroll 2
        for (int nt = 0; nt < 8; nt++) {
            f32x4 acc = {0.f, 0.f, 0.f, 0.f};
            const u16* bp = W2p + nt * 4096 + lane * 8;
            #pragma unroll
            for (int kc = 0; kc < 8; kc++)
                acc = __builtin_amdgcn_mfma_f32_16x16x32_bf16(a[kc], ldbf8(bp + kc * 512), acc, 0, 0, 0);
            int col = nt * 16 + lm;
            float bias = b2[col];
            #pragma unroll
            for (int r = 0; r < 4; r++)
                sA[(w * 16 + q * 4 + r) * 136 + col] = f2bf(sp2(acc[r] + bias));
        }
    }
    // stage 3: ec = h2 @ Wc -> back into sA (frags read before overwrite, wave-private)
    {
        bf16x8 a3[4];
        const u16* ar = sA + (w * 16 + lm) * 136;
        #pragma unroll
        for (int kc = 0; kc < 4; kc++) a3[kc] = ldbf8(ar + kc * 32 + q * 8);
        #pragma unroll 2
        for (int nt = 0; nt < 8; nt++) {
            f32x4 acc = {0.f, 0.f, 0.f, 0.f};
            const u16* bp = Wcp + nt * 2048 + lane * 8;
            #pragma unroll
            for (int kc = 0; kc < 4; kc++)
                acc = __builtin_amdgcn_mfma_f32_16x16x32_bf16(a3[kc], ldbf8(bp + kc * 512), acc, 0, 0, 0);
            int col = nt * 16 + lm;
            #pragma unroll
            for (int r = 0; r < 4; r++)
                sA[(w * 16 + q * 4 + r) * 136 + col] = f2bf(acc[r]);
        }
    }
    __syncthreads();
    // write ec tile to fg f-half (coalesced 256B rows); edge_compute reads then overwrites in-place
    {
        int r = tid >> 2, p = tid & 3;
        int row = base + r;
        if (row < NE) {
            u16* dptr = fg + (size_t)row * 128 + p * 32;
            const u16* sptr = sA + r * 136 + p * 32;
            #pragma unroll
            for (int i = 0; i < 4; i++) *(u16x8*)(dptr + i * 8) = *(const u16x8*)(sptr + i * 8);
        }
    }
}

// ---------------- edge compute: pure gather + edge update streams (NO LDS, NO atomics, NO barriers) ----------------
// 16-lane group per edge; grid-stride. Graph keys from sequential gbk (no batch[] gather).
__global__ __launch_bounds__(256, 6) void edge_compute_kernel(
    const float* __restrict__ ef0, const int* __restrict__ ei, const u8* __restrict__ gbk,
    const u16* __restrict__ nfab, const float* __restrict__ gfd,
    float* __restrict__ ef_out, u16* __restrict__ fg)
{
    int tid = threadIdx.x;
    int grp0 = blockIdx.x * 16 + (tid >> 4);
    int ci  = (tid & 15) * 8;
    int stride = gridDim.x * 16;
    for (int e = grp0; e < NE; e += stride) {
        int s = ei[e], d = ei[NE + e];
        // stream loads first (likely HBM), then gathers (likely L2/L3)
        u16x8 ecv = *(const u16x8*)(fg + (size_t)e * 128 + ci);
        f32x4 e0a = *(const f32x4*)(ef0 + (size_t)e * 128 + ci);
        f32x4 e0b = *(const f32x4*)(ef0 + (size_t)e * 128 + ci + 4);
        u16x8 va  = *(const u16x8*)(nfab + (size_t)s * 256 + ci);
        u16x8 vbs = *(const u16x8*)(nfab + (size_t)s * 256 + 128 + ci);
        u16x8 vad = *(const u16x8*)(nfab + (size_t)d * 256 + ci);
        u16x8 vbd = *(const u16x8*)(nfab + (size_t)d * 256 + 128 + ci);
        int gbf = gbk[e], gbb = gbk[NE + e];
        f32x4 gfa = *(const f32x4*)(gfd + gbf * 128 + ci);
        f32x4 gfa2 = *(const f32x4*)(gfd + gbf * 128 + ci + 4);
        f32x4 gfb = *(const f32x4*)(gfd + gbb * 128 + ci);
        f32x4 gfb2 = *(const f32x4*)(gfd + gbb * 128 + ci + 4);
        u16x8 fv, gv;
        f32x4 oa, ob;
        #pragma unroll
        for (int i = 0; i < 8; i++) {
            float ec = b2f(ecv[i]);
            float gf_f = (i < 4) ? gfa[i & 3] : gfa2[i & 3];
            float gf_b = (i < 4) ? gfb[i & 3] : gfb2[i & 3];
            float f = b2f(va[i])  + b2f(vbd[i]) + ec + gf_f;
            float g = b2f(vad[i]) + b2f(vbs[i]) + ec + gf_b;
            float o = 0.5f * (f + g) + ((i < 4) ? e0a[i & 3] : e0b[i & 3]);
            if (i < 4) oa[i & 3] = o; else ob[i & 3] = o;
            fv[i] = f2bf(f); gv[i] = f2bf(g);
        }
        float* eop = ef_out + (size_t)e * 128 + ci;
        *(f32x4*)(eop)     = oa;
        *(f32x4*)(eop + 4) = ob;
        *(u16x8*)(fg + (size_t)e * 128 + ci) = fv;                // overwrite ec in place
        *(u16x8*)(fg + (size_t)(NE + e) * 128 + ci) = gv;
    }
}

// ---------------- em reduce via MFMA one-hot: em[g][c] = sum_r 1[gbk_r==g] * fg[r][c] ----------------
// A = one-hot [16 x 32] built from gbk; B = fg rows [32 x 16-coltile]. No atomics in the hot loop.
// Numerically identical to f32 adds of bf16 values (MFMA = exact bf16 products, fp32 accumulate).
__global__ __launch_bounds__(256, 4) void em_reduce_kernel(
    const u16* __restrict__ fg, const u8* __restrict__ gbk, float* __restrict__ em32)
{
    __shared__ float s_emw[4][2048];
    int tid = threadIdx.x;
    int w = tid >> 6, lane = tid & 63, q = lane >> 4, lm = lane & 15;
    f32x4 acc[8];
    #pragma unroll
    for (int ct = 0; ct < 8; ct++) acc[ct] = (f32x4){0.f, 0.f, 0.f, 0.f};
    // wave-granular grid-stride over 32-row steps (2E = 32 * 15625 exactly)
    for (int step = blockIdx.x * 4 + w; step < EMR_STEPS; step += EMR_GRID * 4) {
        int rowbase = step * 32;
        // one-hot A fragment: lane holds A[g=lm][k=q*8+j] = (gbk[rowbase+q*8+j] == lm)
        const u32* gp32 = (const u32*)(gbk + rowbase);
        u32 b0 = gp32[q * 2], b1 = gp32[q * 2 + 1];
        u16x8 av;
        #pragma unroll
        for (int j = 0; j < 8; j++) {
            u32 word = (j < 4) ? b0 : b1;
            u32 gj = (word >> (8 * (j & 3))) & 255u;
            av[j] = (gj == (u32)lm) ? (u16)0x3F80 : (u16)0;
        }
        bf16x8 afrag = __builtin_bit_cast(bf16x8, av);
        // B fragments: lane holds B[k=q*8+j][n=lm] = fg[rowbase+q*8+j][ct*16+lm]
        const u16* rb = fg + (size_t)rowbase * 128;
        #pragma unroll
        for (int ct = 0; ct < 8; ct++) {
            u16x8 bv;
            #pragma unroll
            for (int j = 0; j < 8; j++)
                bv[j] = rb[(size_t)(q * 8 + j) * 128 + ct * 16 + lm];
            acc[ct] = __builtin_amdgcn_mfma_f32_16x16x32_bf16(afrag, __builtin_bit_cast(bf16x8, bv), acc[ct], 0, 0, 0);
        }
    }
    // C layout: row g = q*4 + rj, col = ct*16 + lm  -> per-wave LDS slab (plain stores)
    #pragma unroll
    for (int ct = 0; ct < 8; ct++)
        #pragma unroll
        for (int rj = 0; rj < 4; rj++)
            s_emw[w][(q * 4 + rj) * 128 + ct * 16 + lm] = acc[ct][rj];
    __syncthreads();
    float* dstm = em32 + (size_t)(blockIdx.x & (EM_REP - 1)) * 2048;
    for (int i = tid; i < 2048; i += 256) {
        float s = s_emw[0][i] + s_emw[1][i] + s_emw[2][i] + s_emw[3][i];
        unsafeAtomicAdd(&dstm[i], s);
    }
}

// ---------------- node update: CSR gather + efm @ Wn2 via MFMA ----------------
__global__ __launch_bounds__(256) void node_update_kernel(
    const float* __restrict__ nf0, const u16* __restrict__ nfn1,
    const u16* __restrict__ fg, const u32* __restrict__ off,
    const u32* __restrict__ node_cnt, const u32* __restrict__ list,
    const u16* __restrict__ Wn2p, const float* __restrict__ gfn3b, const int* __restrict__ batch,
    float* __restrict__ nf_out, float* __restrict__ nm_acc, u32* __restrict__ nm_cnt)
{
    __shared__ __align__(16) u16 sE[64 * 136];
    __shared__ float s_nm[2048];
    __shared__ u32 s_ncnt[16];
    int tid = threadIdx.x;
    for (int i = tid; i < 2048; i += 256) s_nm[i] = 0.f;
    if (tid < 16) s_ncnt[tid] = 0;
    __syncthreads();
    int base = blockIdx.x * 64;
    {
        int r = tid >> 2, p = tid & 3;
        int n = base + r;
        u16* d = sE + r * 136 + p * 32;
        if (n < NN) {
            u32 o = off[n], c = node_cnt[n];
            float acc[32];
            #pragma unroll
            for (int i = 0; i < 32; i++) acc[i] = 0.f;
            u32 row = (c > 0) ? list[o] : 0;            // prefetch next row index
            for (u32 j = 0; j < c; j++) {
                u32 rcur = row;
                if (j + 1 < c) row = list[o + j + 1];
                const u16* pr = fg + (size_t)rcur * 128 + p * 32;
                #pragma unroll
                for (int i2 = 0; i2 < 4; i2++) {
                    u16x8 v = *(const u16x8*)(pr + i2 * 8);
                    #pragma unroll
                    for (int jj = 0; jj < 8; jj++) acc[i2 * 8 + jj] += b2f(v[jj]);
                }
            }
            float inv = 1.f / fmaxf((float)c, 1.f);
            #pragma unroll
            for (int i2 = 0; i2 < 4; i2++) {
                u16x8 ov;
                #pragma unroll
                for (int jj = 0; jj < 8; jj++) ov[jj] = f2bf(acc[i2 * 8 + jj] * inv);
                *(u16x8*)(d + i2 * 8) = ov;
            }
            if (p == 0) atomicAdd(&s_ncnt[batch[n]], 1u);
        } else {
            u16x8 z = {0,0,0,0,0,0,0,0};
            #pragma unroll
            for (int i = 0; i < 4; i++) *(u16x8*)(d + i * 8) = z;
        }
    }
    __syncthreads();
    int lane = tid & 63, w = tid >> 6, q = lane >> 4, lm = lane & 15;
    int rows[4]; bool ok[4]; int gg[4];
    #pragma unroll
    for (int r = 0; r < 4; r++) {
        rows[r] = base + w * 16 + q * 4 + r;
        ok[r] = rows[r] < NN;
        gg[r] = ok[r] ? batch[rows[r]] : 0;
    }
    bf16x8 a[4];
    const u16* ar = sE + (w * 16 + lm) * 136;
    #pragma unroll
    for (int kc = 0; kc < 4; kc++) a[kc] = ldbf8(ar + kc * 32 + q * 8);
    for (int nt = 0; nt < 8; nt++) {
        f32x4 acc = {0.f, 0.f, 0.f, 0.f};
        const u16* bp = Wn2p + nt * 2048 + lane * 8;
        #pragma unroll
        for (int kc = 0; kc < 4; kc++)
            acc = __builtin_amdgcn_mfma_f32_16x16x32_bf16(a[kc], ldbf8(bp + kc * 512), acc, 0, 0, 0);
        int col = nt * 16 + lm;
        #pragma unroll
        for (int r = 0; r < 4; r++) {
            if (ok[r]) {
                size_t idx = (size_t)rows[r] * 128 + col;
                float upd = acc[r] + b2f(nfn1[idx]) + gfn3b[gg[r] * 128 + col];
                nf_out[idx] = upd + nf0[idx];
                atomicAdd(&s_nm[gg[r] * 128 + col], upd);
            }
        }
    }
    __syncthreads();
    for (int g = 0; g < 16; g++) {
        u32 c = s_ncnt[g];
        if (c) {
            if (tid < 128) unsafeAtomicAdd(&nm_acc[g * 128 + tid], s_nm[g * 128 + tid]);
            if (tid == 0) atomicAdd(&nm_cnt[g], c);
        }
    }
}

// ---------------- global update: one block per graph ----------------
__global__ __launch_bounds__(256) void global_update_kernel(
    const float* __restrict__ gf0, const float* __restrict__ gf_pre,
    const float* __restrict__ em32, const u32* __restrict__ ecnt,
    const float* __restrict__ nm_acc, const u32* __restrict__ nm_cnt,
    const float* __restrict__ gmW, const float* __restrict__ gmb,
    float* __restrict__ gf_out)
{
    __shared__ float s_cat[384];
    int g = blockIdx.x;
    int tid = threadIdx.x;
    for (int i = tid; i < 384; i += 256) {
        int seg = i >> 7, c = i & 127;
        float v;
        if (seg == 0) {
            float s = 0.f;
            for (int r = 0; r < EM_REP; r++) s += em32[(size_t)r * 2048 + g * 128 + c];
            v = s / fmaxf((float)ecnt[g], 1.f);
        } else if (seg == 1) {
            v = nm_acc[g * 128 + c] / fmaxf((float)nm_cnt[g], 1.f);
        } else {
            v = gf_pre[g * 128 + c];
        }
        s_cat[i] = v;
    }
    __syncthreads();
    for (int c = tid; c < 128; c += 256) {
        float acc = gmb[c];
        for (int k = 0; k < 384; k++) acc += s_cat[k] * gmW[k * 128 + c];
        gf_out[g * 128 + c] = acc + gf0[g * 128 + c];
    }
}

// ---------------- launcher ----------------
extern "C" void kernel_launch(void* const* d_in, const int* in_sizes, int n_in,
                              void* d_out, int out_size, void* d_ws, size_t ws_size,
                              hipStream_t stream) {
    const float* nf0 = (const float*)d_in[0];
    const int*   ei  = (const int*)d_in[1];
    const float* ef0 = (const float*)d_in[2];
    const float* gf0 = (const float*)d_in[3];
    const int* batch = (const int*)d_in[4];
    const float *eW1 = (const float*)d_in[5],  *eb1 = (const float*)d_in[6];
    const float *eW2 = (const float*)d_in[7],  *eb2 = (const float*)d_in[8];
    const float *nW1 = (const float*)d_in[9],  *nb1 = (const float*)d_in[10];
    const float *nW2 = (const float*)d_in[11], *nb2 = (const float*)d_in[12];
    const float *gW1 = (const float*)d_in[13], *gb1 = (const float*)d_in[14];
    const float *gW2 = (const float*)d_in[15], *gb2 = (const float*)d_in[16];
    const float *emW = (const float*)d_in[17], *emb = (const float*)d_in[18];
    const float *nmW = (const float*)d_in[19], *nmb = (const float*)d_in[20];
    const float *gmW = (const float*)d_in[21], *gmb = (const float*)d_in[22];

    if (ws_size < WS_NEED) {
        fprintf(stderr, "kernel_launch: ws too small: %zu < %zu\n", ws_size, WS_NEED);
        return;
    }
    char* ws = (char*)d_ws;
    u16* nfab   = (u16*)(ws + OFF_NFA);   // [NN,256] interleaved nfa|nfb
    u16* nfn1   = (u16*)(ws + OFF_NFN1);
    u16* fg     = (u16*)(ws + OFF_FG);
    u32* list   = (u32*)(ws + OFF_LIST);
    u32* ncnt   = (u32*)(ws + OFF_NCNT);
    u32* ecnt   = (u32*)(ws + OFF_ECNT);
    float* em32 = (float*)(ws + OFF_EM32);
    u32* offa   = (u32*)(ws + OFF_OFFA);
    u32* curs   = (u32*)(ws + OFF_CURS);
    u32* bsum   = (u32*)(ws + OFF_BSUM);
    u16* pk     = (u16*)(ws + OFF_PACK);
    u8*  gbk    = (u8*)(ws + OFF_GBK);

    float* nf_out = (float*)d_out;
    float* ef_out = nf_out + (size_t)NN * 128;
    float* gf_out = ef_out + (size_t)NE * 128;

    hipMemsetAsync(ws + OFF_NCNT, 0, ZERO_SZ, stream);

    pack_kernel<<<832, 256, 0, stream>>>(eW1, eW2, nW1, nW2, emW, nmW, pk);
    gdense_kernel<<<16, 256, 0, stream>>>(gf0, gW1, gb1, gW2, gb2, emW, emb, nmW, nmb,
                                          (float*)(ws + OFF_GFP), (float*)(ws + OFF_GFD),
                                          (float*)(ws + OFF_GFN3));
    deg_kernel<<<512, 256, 0, stream>>>(ei, batch, ncnt, ecnt, gbk);
    scan1_kernel<<<NB_SCAN, 256, 0, stream>>>(ncnt, bsum);
    scan2_kernel<<<1, 256, 0, stream>>>(bsum);
    scan3_kernel<<<NB_SCAN, 256, 0, stream>>>(ncnt, bsum, offa, curs);
    fill_kernel<<<512, 256, 0, stream>>>(ei, curs, list);
    mlp_node_kernel<<<(NN + 63) / 64, 256, 0, stream>>>(
        nf0, pk + 65536, nb1, pk + 98304, nb2,
        pk + 131072, pk + 147456, pk + 180224, nfab, nfab + 128, nfn1);
    edge_mlp_kernel<<<(NE + 63) / 64, 256, 0, stream>>>(
        ef0, pk + 0, eb1, pk + 32768, eb2, pk + 163840, fg);
    edge_compute_kernel<<<1536, 256, 0, stream>>>(
        ef0, ei, gbk, nfab, (const float*)(ws + OFF_GFD),
        ef_out, fg);
    em_reduce_kernel<<<EMR_GRID, 256, 0, stream>>>(
        fg, gbk, em32);
    node_update_kernel<<<(NN + 63) / 64, 256, 0, stream>>>(
        nf0, nfn1, fg, offa, ncnt, list,
        pk + 196608, (const float*)(ws + OFF_GFN3), batch,
        nf_out, (float*)(ws + OFF_NMA), (u32*)(ws + OFF_NMC));
    global_update_kernel<<<16, 256, 0, stream>>>(
        gf0, (const float*)(ws + OFF_GFP),
        em32, ecnt,
        (const float*)(ws + OFF_NMA), (const u32*)(ws + OFF_NMC),
        gmW, gmb, gf_out);
}